// Round 9
// baseline (35.136 us; speedup 1.0000x reference)
//
#include <hip/hip_runtime.h>
#include <math.h>

#define DD   768
#define BB   32
#define NTP  256        // target pixels per batch (16x16)
#define NSP  1024       // search pixels per batch (32x32)
#define NT   (BB*NTP)   // 8192 target px
#define NS   (BB*NSP)   // 32768 search px
#define ECH  16         // E-chunks for prep (48 rows each)
#define CHE  (DD/ECH)   // 48
#define NO   8          // channel octants
#define OCH  (DD/NO)    // 96

// ws layout (floats); float4-aligned offsets
#define OFF_UP  0                      // uPart[ECH][DD]
#define OFF_VP  (OFF_UP + ECH*DD)      // vPart[ECH][DD]
#define OFF_K   (OFF_VP + ECH*DD)      // K1,K2 (+pad)
#define OFF_TR0 (OFF_K + 64)           // target R dots [NO][NT]
#define OFF_TS0 (OFF_TR0 + NO*NT)      // target S dots [NO][NT]
#define OFF_SR  (OFF_TS0 + NO*NT)      // search R dots [NO][NS]
#define OFF_SS  (OFF_SR + NO*NS)       // search S dots [NO][NS]
// total ~ 680K floats ~= 2.7 MB

#define A5 0.99500999000499900f        // (1 - LR*LAMBDA)^5

// 17 blocks: 16 compute U/V partials over 48-row chunks of w; 1 computes K1/K2.
__global__ void k_prep(const float* __restrict__ w, const float* __restrict__ cb,
                       const float* __restrict__ gamma, const float* __restrict__ beta,
                       const float* __restrict__ mean, const float* __restrict__ var,
                       const float* __restrict__ fi, float* __restrict__ ws) {
    int bx = blockIdx.x;
    int t = threadIdx.x;
    if (bx < ECH) {
        __shared__ float wu[CHE], wv[CHE];
        if (t < CHE) {
            int e = bx * CHE + t;
            float inv = gamma[e] / sqrtf(var[e] + 1e-5f);
            wv[t] = inv;
            wu[t] = inv * fi[e];
        }
        __syncthreads();
        if (t < 192) {   // one f4-column (4 d's) per thread
            const float4* w4 = (const float4*)w;
            float4 Ru = {0,0,0,0}, Rv = {0,0,0,0};
            #pragma unroll
            for (int j = 0; j < CHE; ++j) {
                float4 x = w4[(size_t)(bx * CHE + j) * 192 + t];
                float a = wu[j], b = wv[j];
                Ru.x += x.x * a; Ru.y += x.y * a; Ru.z += x.z * a; Ru.w += x.w * a;
                Rv.x += x.x * b; Rv.y += x.y * b; Rv.z += x.z * b; Rv.w += x.w * b;
            }
            *(float4*)(ws + OFF_UP + bx * DD + t * 4) = Ru;
            *(float4*)(ws + OFF_VP + bx * DD + t * 4) = Rv;
        }
    } else {
        __shared__ float r1[256], r2[256];
        float a1 = 0.f, a2 = 0.f;
        for (int e = t; e < DD; e += 256) {
            float inv = gamma[e] / sqrtf(var[e] + 1e-5f);
            float x = (cb[e] - mean[e]) * inv + beta[e];
            a1 += x * fi[e];
            a2 += x;
        }
        r1[t] = a1; r2[t] = a2;
        __syncthreads();
        for (int s = 128; s > 0; s >>= 1) {
            if (t < s) { r1[t] += r1[t + s]; r2[t] += r2[t + s]; }
            __syncthreads();
        }
        if (t == 0) { ws[OFF_K] = r1[0]; ws[OFF_K + 1] = r2[0]; }
    }
}

// 1280 uniform blocks = exactly 5/CU.
//   search: 1024 = 32 b x 4 px-groups(256px) x 8 ch-octants(96ch)
//   target:  256 = 32 b x 1 px-group (256px) x 8 ch-octants
// Block = 64 f4-px x 4 subs (24 ch each). Every wave-load = one aligned 1 KB
// contiguous segment. 12-deep rolling prefetch, fully unrolled (static idx).
__global__ __launch_bounds__(256, 5) void k_big(const float* __restrict__ sf,
                                                const float* __restrict__ tf,
                                                float* __restrict__ ws) {
    int bx = blockIdx.x;
    int t = threadIdx.x;
    int pxf4 = t & 63, sub = t >> 6;      // 64 f4-px, 4 channel-subs

    int b, q, oct; bool isS;
    if (bx < 1024) { isS = true;  oct = bx & 7; q = (bx >> 3) & 3; b = bx >> 5; }
    else           { isS = false; int u = bx - 1024; oct = u & 7; q = 0; b = u >> 3; }

    // prologue: this block's 96-ch U/V slice from the 16 prep partials (L2-hot)
    __shared__ float su[OCH], sv[OCH];
    if (t < 24) {
        float4 U = {0,0,0,0};
        #pragma unroll
        for (int ec = 0; ec < ECH; ++ec) {
            float4 a = ((const float4*)(ws + OFF_UP))[ec * 192 + oct * 24 + t];
            U.x += a.x; U.y += a.y; U.z += a.z; U.w += a.w;
        }
        ((float4*)su)[t] = U;
    } else if (t < 48) {
        int j = t - 24;
        float4 V = {0,0,0,0};
        #pragma unroll
        for (int ec = 0; ec < ECH; ++ec) {
            float4 c = ((const float4*)(ws + OFF_VP))[ec * 192 + oct * 24 + j];
            V.x += c.x; V.y += c.y; V.z += c.z; V.w += c.w;
        }
        ((float4*)sv)[j] = V;
    }
    __syncthreads();

    const float4* base;
    int STR;
    float4 *oR, *oS;
    if (isS) {
        base = (const float4*)sf + ((size_t)b * DD + oct * OCH + sub * 24) * (NSP/4) + q * 64 + pxf4;
        STR = NSP / 4;                    // 256
        int g4 = b * 256 + q * 64 + pxf4;
        oR = (float4*)(ws + OFF_SR) + oct * (NS/4) + g4;
        oS = (float4*)(ws + OFF_SS) + oct * (NS/4) + g4;
    } else {
        base = (const float4*)tf + ((size_t)b * DD + oct * OCH + sub * 24) * (NTP/4) + pxf4;
        STR = NTP / 4;                    // 64
        int g4 = b * 64 + pxf4;
        oR = (float4*)(ws + OFF_TR0) + oct * (NT/4) + g4;
        oS = (float4*)(ws + OFF_TS0) + oct * (NT/4) + g4;
    }

    // 24 channels/thread, 12-deep rolling prefetch
    float4 accR = {0,0,0,0}, accS = {0,0,0,0};
    float4 buf[12];
    #pragma unroll
    for (int k = 0; k < 12; ++k) buf[k] = base[(size_t)k * STR];
    #pragma unroll
    for (int i = 0; i < 24; ++i) {
        float4 v = buf[i % 12];
        if (i < 12) buf[i % 12] = base[(size_t)(i + 12) * STR];
        float u = su[sub * 24 + i], vb = sv[sub * 24 + i];
        accR.x += v.x * u;  accR.y += v.y * u;  accR.z += v.z * u;  accR.w += v.w * u;
        accS.x += v.x * vb; accS.y += v.y * vb; accS.z += v.z * vb; accS.w += v.w * vb;
    }

    // reduce over 4 subs
    __shared__ float4 redR[4][64], redS[4][64];
    redR[sub][pxf4] = accR; redS[sub][pxf4] = accS;
    __syncthreads();
    if (sub < 2) {
        float4 a = redR[sub + 2][pxf4], m = redR[sub][pxf4];
        m.x += a.x; m.y += a.y; m.z += a.z; m.w += a.w; redR[sub][pxf4] = m;
        float4 c = redS[sub + 2][pxf4], n = redS[sub][pxf4];
        n.x += c.x; n.y += c.y; n.z += c.z; n.w += c.w; redS[sub][pxf4] = n;
    }
    __syncthreads();
    if (sub == 0) {
        float4 a = redR[1][pxf4], m = redR[0][pxf4];
        m.x += a.x; m.y += a.y; m.z += a.z; m.w += a.w;
        float4 c = redS[1][pxf4], n = redS[0][pxf4];
        n.x += c.x; n.y += c.y; n.z += c.z; n.w += c.w;
        *oR = m; *oS = n;
    }
}

// Per batch: filter iterations from target dots (sum 8 octants), then final
// output combine (4 search px per thread).
__global__ void k_final(const float* __restrict__ mask, const float* __restrict__ ws,
                        float* __restrict__ out) {
    int b = blockIdx.x;
    int p = threadIdx.x;
    int lane = p & 63, wv = p >> 6;
    int h = p >> 4, w = p & 15;
    float K1 = ws[OFF_K], K2 = ws[OFF_K + 1];
    float r0 = K1, s0 = K2;
    #pragma unroll
    for (int o = 0; o < NO; ++o) {
        r0 += ws[OFF_TR0 + o * NT + b * 256 + p];
        s0 += ws[OFF_TS0 + o * NT + b * 256 + p];
    }
    float m = mask[b * 256 + p];
    __shared__ float cross[4];
    auto bsum = [&](float v) -> float {
        #pragma unroll
        for (int o = 32; o > 0; o >>= 1) v += __shfl_xor(v, o, 64);
        if (lane == 0) cross[wv] = v;
        __syncthreads();
        float r = cross[0] + cross[1] + cross[2] + cross[3];
        __syncthreads();
        return r;
    };
    float msum = bsum(m);
    float sy = bsum(m * (float)h);
    float sx = bsum(m * (float)w);
    msum = fmaxf(msum, 1.0f);
    float cy = sy / msum, cx = sx / msum;
    float dx = (float)w - cx, dy = (float)h - cy;
    float label = expf(-(dx * dx + dy * dy) * 0.125f);   // 2*sigma^2 = 8
    float A = 1.0f, c = 0.0f;
    const float decay = 1.0f - 0.1f * 0.01f;
    #pragma unroll
    for (int it = 0; it < 5; ++it) {
        float resp = A * r0 + c * s0;
        float gc = (1.0f - resp * label > 0.0f) ? (-label * m) : 0.0f;
        float g = bsum(gc) * (1.0f / 256.0f);
        c = decay * c - 0.1f * g;
        A *= decay;
    }
    // combine: 4 search px per thread
    int g4 = b * 256 + p;                 // f4 index into [NS/4]
    float4 R = {K1, K1, K1, K1}, S = {K2, K2, K2, K2};
    #pragma unroll
    for (int o = 0; o < NO; ++o) {
        float4 a = ((const float4*)(ws + OFF_SR))[o * (NS/4) + g4];
        float4 d = ((const float4*)(ws + OFF_SS))[o * (NS/4) + g4];
        R.x += a.x; R.y += a.y; R.z += a.z; R.w += a.w;
        S.x += d.x; S.y += d.y; S.z += d.z; S.w += d.w;
    }
    float4 o;
    o.x = A5 * R.x + c * S.x;
    o.y = A5 * R.y + c * S.y;
    o.z = A5 * R.z + c * S.z;
    o.w = A5 * R.w + c * S.w;
    ((float4*)out)[g4] = o;
}

extern "C" void kernel_launch(void* const* d_in, const int* in_sizes, int n_in,
                              void* d_out, int out_size, void* d_ws, size_t ws_size,
                              hipStream_t stream) {
    const float* sf    = (const float*)d_in[0];
    const float* tf    = (const float*)d_in[1];
    const float* mask  = (const float*)d_in[2];
    const float* w     = (const float*)d_in[3];
    const float* cb    = (const float*)d_in[4];
    const float* gamma = (const float*)d_in[5];
    const float* beta  = (const float*)d_in[6];
    const float* mean  = (const float*)d_in[7];
    const float* var   = (const float*)d_in[8];
    const float* fi    = (const float*)d_in[9];
    float* out = (float*)d_out;
    float* ws  = (float*)d_ws;

    k_prep <<<ECH + 1, 256, 0, stream>>>(w, cb, gamma, beta, mean, var, fi, ws);
    k_big  <<<1280,    256, 0, stream>>>(sf, tf, ws);
    k_final<<<BB,      256, 0, stream>>>(mask, ws, out);
}